// Round 12
// baseline (1000.571 us; speedup 1.0000x reference)
//
#include <hip/hip_runtime.h>

#define PRESCALE 2.8853900817779268f   // 2*log2(e): exp2(PRESCALE*x) == e^{2x}

// ---- ATTRIBUTION ROUND: per-kernel rep loops (idempotent re-execution) ----
#define PREP_REPS  32
#define GEMM_REPS  24
#define AI_REPS    48
#define SCORE_REPS 8
#define CTX_REPS   24
#define KEEP() asm volatile("" ::: "memory")

typedef short s16;
typedef unsigned short u16;
typedef unsigned int u32;
typedef __attribute__((ext_vector_type(8))) short short8v;  // 8 bf16 (4 VGPRs)
typedef __attribute__((ext_vector_type(4))) float f4;

#if __has_builtin(__builtin_amdgcn_exp2f)
#define EXP2(x) __builtin_amdgcn_exp2f(x)
#else
static __device__ inline float exp2_raw(float x){ float r; asm("v_exp_f32 %0, %1":"=v"(r):"v"(x)); return r; }
#define EXP2(x) exp2_raw(x)
#endif
#if __has_builtin(__builtin_amdgcn_rcpf)
#define RCP(x) __builtin_amdgcn_rcpf(x)
#else
static __device__ inline float rcp_raw(float x){ float r; asm("v_rcp_f32 %0, %1":"=v"(r):"v"(x)); return r; }
#define RCP(x) rcp_raw(x)
#endif

__device__ inline u16 f2bf(float f){
  union{u32 i; float f;} v; v.f = f;
  u32 r = v.i + 0x7fffu + ((v.i >> 16) & 1u);
  return (u16)(r >> 16);
}

// ---------------- K0: conversions + emb gather. 512 blocks, grid-stride.
__global__ __launch_bounds__(256) void k_prep(
    const float* __restrict__ W_img, const float* __restrict__ W_ai,
    const float* __restrict__ W_aw,  const float* __restrict__ img_feat,
    const int* __restrict__ question, const float* __restrict__ emb,
    s16* __restrict__ Wb, s16* __restrict__ Xb, s16* __restrict__ Eb,
    float* __restrict__ out){
  for (int rep = 0; rep < PREP_REPS; ++rep){
    for (int g = blockIdx.x*256 + threadIdx.x; g < 360448; g += gridDim.x*256){
      if (g < 196608){
        const int i = g*4, w = i >> 18;
        const float sc = (w == 0) ? 1.f : PRESCALE;
        const float* src = (w==0) ? W_img : ((w==1) ? W_ai : W_aw);
        float4 v = *reinterpret_cast<const float4*>(src + (i & 262143));
        ushort4 o; o.x=f2bf(v.x*sc); o.y=f2bf(v.y*sc); o.z=f2bf(v.z*sc); o.w=f2bf(v.w*sc);
        *reinterpret_cast<ushort4*>(Wb + i) = o;
      } else if (g < 229376){
        const int i = (g - 196608)*4;
        ushort4 o = make_ushort4(0,0,0,0);
        if ((i >> 9) < 196){
          float4 v = *reinterpret_cast<const float4*>(img_feat + i);
          o.x=f2bf(v.x); o.y=f2bf(v.y); o.z=f2bf(v.z); o.w=f2bf(v.w);
        }
        *reinterpret_cast<ushort4*>(Xb + i) = o;
      } else {
        const int i = (g - 229376)*4;
        const int t = i >> 9, c = i & 511;
        float4 v = *reinterpret_cast<const float4*>(emb + (size_t)question[t]*512 + c);
        *reinterpret_cast<float4*>(out + (size_t)t*1024 + 512 + c) = v;
        ushort4 o; o.x=f2bf(v.x); o.y=f2bf(v.y); o.z=f2bf(v.z); o.w=f2bf(v.w);
        *reinterpret_cast<ushort4*>(Eb + i) = o;
      }
    }
    KEEP();
  }
}

// 64x64 MFMA tile core: D[i][j] = sum_k A[i][k]*B[j][k], K=512 bf16.
__device__ inline void mfma_core(const s16* __restrict__ A, const s16* __restrict__ B,
                                 int m0, int n0, int lr, int lg, f4 acc[2][2]){
  const s16* pa0 = A + (size_t)(m0 + lr)*512 + lg*8;
  const s16* pa1 = pa0 + 16*512;
  const s16* pb0 = B + (size_t)(n0 + lr)*512 + lg*8;
  const s16* pb1 = pb0 + 16*512;
  #pragma unroll 4
  for (int k = 0; k < 512; k += 32){
    short8v a0 = *reinterpret_cast<const short8v*>(pa0 + k);
    short8v a1 = *reinterpret_cast<const short8v*>(pa1 + k);
    short8v b0 = *reinterpret_cast<const short8v*>(pb0 + k);
    short8v b1 = *reinterpret_cast<const short8v*>(pb1 + k);
    acc[0][0] = __builtin_amdgcn_mfma_f32_16x16x32_bf16(a0, b0, acc[0][0], 0, 0, 0);
    acc[0][1] = __builtin_amdgcn_mfma_f32_16x16x32_bf16(a0, b1, acc[0][1], 0, 0, 0);
    acc[1][0] = __builtin_amdgcn_mfma_f32_16x16x32_bf16(a1, b0, acc[1][0], 0, 0, 0);
    acc[1][1] = __builtin_amdgcn_mfma_f32_16x16x32_bf16(a1, b1, acc[1][1], 0, 0, 0);
  }
}

// ---------------- K1: img GEMM (blocks 0..31) + AWT GEMM (blocks 32..159).
__global__ __launch_bounds__(256) void k_gemms(
    const s16* __restrict__ Xb, const s16* __restrict__ Wb_img,
    const s16* __restrict__ Wb_aw, const s16* __restrict__ Eb,
    const float* __restrict__ b_img, const float* __restrict__ b_aw,
    float* __restrict__ img, s16* __restrict__ img_b,
    float* __restrict__ AWT4){
  const int tid = threadIdx.x, w = tid>>6, l = tid&63;
  const int lr = l & 15, lg = l >> 4;
  for (int rep = 0; rep < GEMM_REPS; ++rep){
    f4 acc[2][2] = {};
    if (blockIdx.x < 32){
      const int m0 = (blockIdx.x >> 3)*64 + (w>>1)*32;
      const int n0 = (blockIdx.x & 7)*64 + (w&1)*32;
      mfma_core(Xb, Wb_img, m0, n0, lr, lg, acc);
      #pragma unroll
      for (int i = 0; i < 2; ++i){
        #pragma unroll
        for (int j = 0; j < 2; ++j){
          const int nn = n0 + j*16 + lr;
          const float bc = b_img[nn];
          #pragma unroll
          for (int p = 0; p < 4; ++p){
            const int mm = m0 + i*16 + lg*4 + p;
            float v = fmaxf(acc[i][j][p] + bc, 0.f);
            img[(size_t)mm*512 + nn] = v;
            img_b[(size_t)mm*512 + nn] = (s16)f2bf(v);
          }
        }
      }
    } else {
      const int blk = blockIdx.x - 32;
      const int m0 = (blk >> 4)*64 + (w>>1)*32;     // h
      const int n0 = (blk & 15)*64 + (w&1)*32;      // t
      mfma_core(Wb_aw, Eb, m0, n0, lr, lg, acc);
      #pragma unroll
      for (int i = 0; i < 2; ++i){
        const int mb = m0 + i*16 + lg*4;            // h = mb+p, mb%4==0
        #pragma unroll
        for (int j = 0; j < 2; ++j){
          const int nn = n0 + j*16 + lr;
          f4 o;
          #pragma unroll
          for (int p = 0; p < 4; ++p)
            o[p] = acc[i][j][p] + b_aw[mb+p]*PRESCALE;
          *reinterpret_cast<f4*>(AWT4 + (size_t)(mb>>2)*4096 + nn*4) = o;
        }
      }
    }
    KEEP();
  }
}

// ---------------- K2: AI = img_b @ Wb_aiT (PRESCALE folded in Wb_ai). 32 blocks.
__global__ __launch_bounds__(256) void k_ai(
    const s16* __restrict__ img_b, const s16* __restrict__ Wb_ai,
    float* __restrict__ AI){
  const int tid = threadIdx.x, w = tid>>6, l = tid&63;
  const int lr = l & 15, lg = l >> 4;
  const int m0 = (blockIdx.x >> 3)*64 + (w>>1)*32;
  const int n0 = (blockIdx.x & 7)*64 + (w&1)*32;
  for (int rep = 0; rep < AI_REPS; ++rep){
    f4 acc[2][2] = {};
    mfma_core(img_b, Wb_ai, m0, n0, lr, lg, acc);
    #pragma unroll
    for (int i = 0; i < 2; ++i)
      #pragma unroll
      for (int j = 0; j < 2; ++j){
        const int nn = n0 + j*16 + lr;
        #pragma unroll
        for (int p = 0; p < 4; ++p){
          const int mm = m0 + i*16 + lg*4 + p;
          AI[(size_t)mm*512 + nn] = acc[i][j][p];
        }
      }
    KEEP();
  }
}

// ---------------- K3: score, h-chunked with aw in registers. grid(40,8,2) x 512.
#define RB5 5
__global__ __launch_bounds__(512) void k_score(
    const float* __restrict__ AI, const float* __restrict__ AWT4,
    const float* __restrict__ w_att, float* __restrict__ STp){
  __shared__ float ais[RB5][64];
  __shared__ float wsh[64];
  const int tid = threadIdx.x, w = tid>>6, l = tid&63;
  const int rr = blockIdx.x, hc = blockIdx.y, th = blockIdx.z;
  const int r0 = rr*RB5, h0 = hc*64;
  for (int rep = 0; rep < SCORE_REPS; ++rep){
    if (tid < 80){                      // stage 5x64 AI tile (row-clamped)
      const int i = tid >> 4, j = tid & 15;
      const int r = min(r0 + i, 195);
      *reinterpret_cast<f4*>(&ais[i][j*4]) =
          *reinterpret_cast<const f4*>(AI + (size_t)r*512 + h0 + j*4);
    } else if (tid < 96){               // stage w_att chunk
      const int j = tid - 80;
      *reinterpret_cast<f4*>(&wsh[j*4]) =
          *reinterpret_cast<const f4*>(w_att + h0 + j*4);
    }
    const int t = th*512 + w*64 + l;
    const int hg0 = hc*16;
    f4 awr[16];                         // aw[h][t] for the 64-h chunk, per-lane
    #pragma unroll
    for (int j = 0; j < 16; ++j)
      awr[j] = *reinterpret_cast<const f4*>(AWT4 + (size_t)(hg0+j)*4096 + t*4);
    __syncthreads();
    #pragma unroll
    for (int i = 0; i < RB5; ++i){
      const int r = r0 + i;
      if (r >= 196) break;
      float a0=0.f, a1=0.f, a2=0.f, a3=0.f;
      #pragma unroll
      for (int j = 0; j < 16; ++j){
        f4 av = *reinterpret_cast<const f4*>(&ais[i][j*4]);
        f4 wv = *reinterpret_cast<const f4*>(&wsh[j*4]);
        a0 += wv.x*RCP(EXP2(av.x+awr[j].x)+1.f);
        a1 += wv.y*RCP(EXP2(av.y+awr[j].y)+1.f);
        a2 += wv.z*RCP(EXP2(av.z+awr[j].z)+1.f);
        a3 += wv.w*RCP(EXP2(av.w+awr[j].w)+1.f);
      }
      STp[((size_t)hc<<18) + (size_t)r*1024 + t] = (a0+a1)+(a2+a3);
    }
    __syncthreads();
    KEEP();
  }
}

// ---------------- K4: sum partials + softmax(-2*ST) (fold /196) + ctx = w @ img.
__global__ __launch_bounds__(256) void k_ctx(
    const float* __restrict__ STp, const float* __restrict__ img,
    float* __restrict__ out){
  __shared__ float wgt[196][16];
  __shared__ float red[16][16];
  const int tid = threadIdx.x;
  const int t0 = blockIdx.x*16, e0 = blockIdx.y*64;
  const int rs = tid>>4, tl = tid&15;
  for (int rep = 0; rep < CTX_REPS; ++rep){
    float m = 1e30f;
    for (int k = 0; k < 13; ++k){
      const int r = rs + 16*k;
      if (r < 196){
        float s = 0.f;
        #pragma unroll
        for (int c = 0; c < 8; ++c)
          s += STp[((size_t)c<<18) + (size_t)r*1024 + t0 + tl];
        wgt[r][tl] = s;
        m = fminf(m, s);
      }
    }
    red[rs][tl] = m;
    __syncthreads();
    if (tid < 16){
      float mm = red[0][tid];
      #pragma unroll
      for (int i = 1; i < 16; ++i) mm = fminf(mm, red[i][tid]);
      red[0][tid] = mm;
    }
    __syncthreads();
    const float mt = red[0][tl];
    float sum = 0.f;
    for (int k = 0; k < 13; ++k){
      const int r = rs + 16*k;
      if (r < 196){
        float p = EXP2(PRESCALE*(mt - wgt[r][tl]));
        wgt[r][tl] = p;
        sum += p;
      }
    }
    __syncthreads();
    red[rs][tl] = sum;
    __syncthreads();
    if (tid < 16){
      float ss = 0.f;
      #pragma unroll
      for (int i = 0; i < 16; ++i) ss += red[i][tid];
      red[0][tid] = 1.f / (ss * 196.f);
    }
    __syncthreads();
    const float inv = red[0][tl];
    for (int k = 0; k < 13; ++k){
      const int r = rs + 16*k;
      if (r < 196) wgt[r][tl] *= inv;
    }
    __syncthreads();

    const int e = e0 + (tid & 63), tq = tid >> 6;
    float acc[4] = {0.f, 0.f, 0.f, 0.f};
    const float* ip = img + e;
    #pragma unroll 4
    for (int r = 0; r < 196; ++r){
      const float f = ip[(size_t)r*512];
      float4 w4 = *reinterpret_cast<const float4*>(&wgt[r][tq*4]);
      acc[0] += w4.x*f; acc[1] += w4.y*f; acc[2] += w4.z*f; acc[3] += w4.w*f;
    }
    #pragma unroll
    for (int j = 0; j < 4; ++j)
      out[(size_t)(t0 + tq*4 + j)*1024 + e] = acc[j];
    __syncthreads();
    KEEP();
  }
}

extern "C" void kernel_launch(void* const* d_in, const int* in_sizes, int n_in,
                              void* d_out, int out_size, void* d_ws, size_t ws_size,
                              hipStream_t stream) {
  const int*   question = (const int*)d_in[0];
  const float* img_feat = (const float*)d_in[1];
  const float* emb      = (const float*)d_in[2];
  const float* W_img    = (const float*)d_in[3];
  const float* b_img    = (const float*)d_in[4];
  const float* W_ai     = (const float*)d_in[5];
  const float* W_aw     = (const float*)d_in[6];
  const float* b_aw     = (const float*)d_in[7];
  const float* w_att    = (const float*)d_in[8];
  float* out = (float*)d_out;

  char* ws = (char*)d_ws;
  s16*   Wb    = (s16*)(ws);                  // 3x512x512 bf16 = 1572864 B
  s16*   Xb    = (s16*)(ws + 1572864);        // 256x512 bf16   = 262144 B
  s16*   Eb    = (s16*)(ws + 1835008);        // 1024x512 bf16  = 1048576 B
  float* img   = (float*)(ws + 2883584);      // 256x512 f32    = 524288 B
  s16*   img_b = (s16*)(ws + 3407872);        // 256x512 bf16   = 262144 B
  float* AI    = (float*)(ws + 3670016);      // 256x512 f32    = 524288 B
  float* AWT4  = (float*)(ws + 4194304);      // 128x1024x4 f32 = 2097152 B
  float* STp   = (float*)(ws + 6291456);      // 8x256x1024 f32 = 8388608 B

  hipLaunchKernelGGL(k_prep,  dim3(512),    dim3(256), 0, stream,
                     W_img, W_ai, W_aw, img_feat, question, emb, Wb, Xb, Eb, out);
  hipLaunchKernelGGL(k_gemms, dim3(160),    dim3(256), 0, stream,
                     Xb, Wb, Wb + 2*262144, Eb, b_img, b_aw, img, img_b, AWT4);
  hipLaunchKernelGGL(k_ai,    dim3(32),     dim3(256), 0, stream,
                     img_b, Wb + 262144, AI);
  hipLaunchKernelGGL(k_score, dim3(40,8,2), dim3(512), 0, stream,
                     AI, AWT4, w_att, STp);
  hipLaunchKernelGGL(k_ctx,   dim3(64,8),   dim3(256), 0, stream, STp, img, out);
}

// Round 13
// 79.391 us; speedup vs baseline: 12.6031x; 12.6031x over previous
//
#include <hip/hip_runtime.h>

#define PRESCALE 2.8853900817779268f   // 2*log2(e): exp2(PRESCALE*x) == e^{2x}

typedef short s16;
typedef unsigned short u16;
typedef unsigned int u32;
typedef __attribute__((ext_vector_type(8))) short short8v;  // 8 bf16 (4 VGPRs)
typedef __attribute__((ext_vector_type(4))) float f4;

#if __has_builtin(__builtin_amdgcn_exp2f)
#define EXP2(x) __builtin_amdgcn_exp2f(x)
#else
static __device__ inline float exp2_raw(float x){ float r; asm("v_exp_f32 %0, %1":"=v"(r):"v"(x)); return r; }
#define EXP2(x) exp2_raw(x)
#endif
#if __has_builtin(__builtin_amdgcn_rcpf)
#define RCP(x) __builtin_amdgcn_rcpf(x)
#else
static __device__ inline float rcp_raw(float x){ float r; asm("v_rcp_f32 %0, %1":"=v"(r):"v"(x)); return r; }
#define RCP(x) rcp_raw(x)
#endif

__device__ inline u16 f2bf(float f){
  union{u32 i; float f;} v; v.f = f;
  u32 r = v.i + 0x7fffu + ((v.i >> 16) & 1u);
  return (u16)(r >> 16);
}

// ---------------- K0: conversions + emb gather. 512 blocks, grid-stride.
__global__ __launch_bounds__(256) void k_prep(
    const float* __restrict__ W_img, const float* __restrict__ W_ai,
    const float* __restrict__ W_aw,  const float* __restrict__ img_feat,
    const int* __restrict__ question, const float* __restrict__ emb,
    s16* __restrict__ Wb, s16* __restrict__ Xb, s16* __restrict__ Eb,
    float* __restrict__ out){
  for (int g = blockIdx.x*256 + threadIdx.x; g < 360448; g += gridDim.x*256){
    if (g < 196608){                    // 3 weights -> bf16 (PRESCALE on W_ai, W_aw)
      const int i = g*4, w = i >> 18;
      const float sc = (w == 0) ? 1.f : PRESCALE;
      const float* src = (w==0) ? W_img : ((w==1) ? W_ai : W_aw);
      float4 v = *reinterpret_cast<const float4*>(src + (i & 262143));
      ushort4 o; o.x=f2bf(v.x*sc); o.y=f2bf(v.y*sc); o.z=f2bf(v.z*sc); o.w=f2bf(v.w*sc);
      *reinterpret_cast<ushort4*>(Wb + i) = o;
    } else if (g < 229376){             // Xb 256x512 bf16, zero-pad rows >=196
      const int i = (g - 196608)*4;
      ushort4 o = make_ushort4(0,0,0,0);
      if ((i >> 9) < 196){
        float4 v = *reinterpret_cast<const float4*>(img_feat + i);
        o.x=f2bf(v.x); o.y=f2bf(v.y); o.z=f2bf(v.z); o.w=f2bf(v.w);
      }
      *reinterpret_cast<ushort4*>(Xb + i) = o;
    } else {                            // Eb 1024x512 bf16 + f32 copy to out[:,512:]
      const int i = (g - 229376)*4;
      const int t = i >> 9, c = i & 511;
      float4 v = *reinterpret_cast<const float4*>(emb + (size_t)question[t]*512 + c);
      *reinterpret_cast<float4*>(out + (size_t)t*1024 + 512 + c) = v;
      ushort4 o; o.x=f2bf(v.x); o.y=f2bf(v.y); o.z=f2bf(v.z); o.w=f2bf(v.w);
      *reinterpret_cast<ushort4*>(Eb + i) = o;
    }
  }
}

// 64x64 MFMA tile core: D[i][j] = sum_k A[i][k]*B[j][k], K=512 bf16.
__device__ inline void mfma_core(const s16* __restrict__ A, const s16* __restrict__ B,
                                 int m0, int n0, int lr, int lg, f4 acc[2][2]){
  const s16* pa0 = A + (size_t)(m0 + lr)*512 + lg*8;
  const s16* pa1 = pa0 + 16*512;
  const s16* pb0 = B + (size_t)(n0 + lr)*512 + lg*8;
  const s16* pb1 = pb0 + 16*512;
  #pragma unroll 4
  for (int k = 0; k < 512; k += 32){
    short8v a0 = *reinterpret_cast<const short8v*>(pa0 + k);
    short8v a1 = *reinterpret_cast<const short8v*>(pa1 + k);
    short8v b0 = *reinterpret_cast<const short8v*>(pb0 + k);
    short8v b1 = *reinterpret_cast<const short8v*>(pb1 + k);
    acc[0][0] = __builtin_amdgcn_mfma_f32_16x16x32_bf16(a0, b0, acc[0][0], 0, 0, 0);
    acc[0][1] = __builtin_amdgcn_mfma_f32_16x16x32_bf16(a0, b1, acc[0][1], 0, 0, 0);
    acc[1][0] = __builtin_amdgcn_mfma_f32_16x16x32_bf16(a1, b0, acc[1][0], 0, 0, 0);
    acc[1][1] = __builtin_amdgcn_mfma_f32_16x16x32_bf16(a1, b1, acc[1][1], 0, 0, 0);
  }
}

// ---------------- K1: img GEMM (blocks 0..31) + AWT GEMM (blocks 32..159).
__global__ __launch_bounds__(256) void k_gemms(
    const s16* __restrict__ Xb, const s16* __restrict__ Wb_img,
    const s16* __restrict__ Wb_aw, const s16* __restrict__ Eb,
    const float* __restrict__ b_img, const float* __restrict__ b_aw,
    float* __restrict__ img, s16* __restrict__ img_b,
    float* __restrict__ AWT4){
  const int tid = threadIdx.x, w = tid>>6, l = tid&63;
  const int lr = l & 15, lg = l >> 4;
  f4 acc[2][2] = {};
  if (blockIdx.x < 32){
    const int m0 = (blockIdx.x >> 3)*64 + (w>>1)*32;
    const int n0 = (blockIdx.x & 7)*64 + (w&1)*32;
    mfma_core(Xb, Wb_img, m0, n0, lr, lg, acc);
    #pragma unroll
    for (int i = 0; i < 2; ++i){
      #pragma unroll
      for (int j = 0; j < 2; ++j){
        const int nn = n0 + j*16 + lr;
        const float bc = b_img[nn];
        #pragma unroll
        for (int p = 0; p < 4; ++p){
          const int mm = m0 + i*16 + lg*4 + p;
          float v = fmaxf(acc[i][j][p] + bc, 0.f);
          img[(size_t)mm*512 + nn] = v;
          img_b[(size_t)mm*512 + nn] = (s16)f2bf(v);
        }
      }
    }
  } else {
    const int blk = blockIdx.x - 32;
    const int m0 = (blk >> 4)*64 + (w>>1)*32;     // h
    const int n0 = (blk & 15)*64 + (w&1)*32;      // t
    mfma_core(Wb_aw, Eb, m0, n0, lr, lg, acc);
    #pragma unroll
    for (int i = 0; i < 2; ++i){
      const int mb = m0 + i*16 + lg*4;            // h = mb+p, mb%4==0
      #pragma unroll
      for (int j = 0; j < 2; ++j){
        const int nn = n0 + j*16 + lr;
        f4 o;
        #pragma unroll
        for (int p = 0; p < 4; ++p)
          o[p] = acc[i][j][p] + b_aw[mb+p]*PRESCALE;
        *reinterpret_cast<f4*>(AWT4 + (size_t)(mb>>2)*4096 + nn*4) = o;
      }
    }
  }
}

// ---------------- K2: score with per-block AI-MFMA. grid(26,8,2) x 512 thr.
// Block owns: r-tile 8 (r0=bx*8, uses rows 0..7 of a 16-row MFMA tile),
// h-chunk 64 (h0=by*64), t-range 512 (tb*512; wave w -> t = +w*64+lane).
// Phase A: waves 0..3 MFMA  ais[16][h0:h0+64] = img_b[16r] @ Wb_ai[64h]^T (k=512).
// Phase B: STp[hc][r][t] = sum_h w[h]*rcp(exp2(ais[r][h]+AW'[h][t])+1).
// softmax(score) == softmax(-2*sum_hc STp). Rows r>=196 garbage, never read.
__global__ __launch_bounds__(512) void k_score(
    const s16* __restrict__ img_b, const s16* __restrict__ Wb_ai,
    const float* __restrict__ AWT4, const float* __restrict__ w_att,
    float* __restrict__ STp){
  __shared__ float ais[16][68];     // pad 68: phase-A store 2-way, phase-B broadcast
  __shared__ float wsh[64];
  const int tid = threadIdx.x, w = tid>>6, l = tid&63;
  const int lr = l & 15, lg = l >> 4;
  const int r0 = blockIdx.x*8, h0 = blockIdx.y*64;

  if (w < 4){                       // phase A: wave w computes 16x16 frag, h-sub w*16
    const s16* pa = img_b + (size_t)(r0 + lr)*512 + lg*8;
    const s16* pb = Wb_ai + (size_t)(h0 + w*16 + lr)*512 + lg*8;
    f4 acc = {};
    #pragma unroll 4
    for (int ks = 0; ks < 16; ++ks){
      short8v a = *reinterpret_cast<const short8v*>(pa + ks*32);
      short8v b = *reinterpret_cast<const short8v*>(pb + ks*32);
      acc = __builtin_amdgcn_mfma_f32_16x16x32_bf16(a, b, acc, 0, 0, 0);
    }
    #pragma unroll
    for (int p = 0; p < 4; ++p)
      ais[lg*4 + p][w*16 + lr] = acc[p];   // D: col(h)=lane&15, row(r)=(lane>>4)*4+p
  }
  if (tid < 16)
    *reinterpret_cast<f4*>(&wsh[tid*4]) =
        *reinterpret_cast<const f4*>(w_att + h0 + tid*4);
  __syncthreads();

  const int t = blockIdx.z*512 + w*64 + l;
  const int hg0 = blockIdx.y*16;    // AWT4 h-group base (4 h per group)
  f4 awr[16];                       // AW'[h0..h0+63][t] per-lane
  #pragma unroll
  for (int j = 0; j < 16; ++j)
    awr[j] = *reinterpret_cast<const f4*>(AWT4 + (size_t)(hg0+j)*4096 + t*4);

  #pragma unroll
  for (int i = 0; i < 8; ++i){
    const int r = r0 + i;           // 0..207 < 256 (STp row capacity)
    float a0=0.f, a1=0.f, a2=0.f, a3=0.f;
    #pragma unroll
    for (int j = 0; j < 16; ++j){
      f4 av = *reinterpret_cast<const f4*>(&ais[i][j*4]);   // wave-broadcast
      f4 wv = *reinterpret_cast<const f4*>(&wsh[j*4]);
      a0 += wv.x*RCP(EXP2(av.x+awr[j].x)+1.f);
      a1 += wv.y*RCP(EXP2(av.y+awr[j].y)+1.f);
      a2 += wv.z*RCP(EXP2(av.z+awr[j].z)+1.f);
      a3 += wv.w*RCP(EXP2(av.w+awr[j].w)+1.f);
    }
    STp[((size_t)blockIdx.y<<18) + (size_t)r*1024 + t] = (a0+a1)+(a2+a3);
  }
}

// ---------------- K3: sum partials + softmax(-2*ST) (fold /196) + ctx = w @ img.
__global__ __launch_bounds__(256) void k_ctx(
    const float* __restrict__ STp, const float* __restrict__ img,
    float* __restrict__ out){
  __shared__ float wgt[196][16];
  __shared__ float red[16][16];
  const int tid = threadIdx.x;
  const int t0 = blockIdx.x*16, e0 = blockIdx.y*64;
  const int rs = tid>>4, tl = tid&15;

  float m = 1e30f;
  for (int k = 0; k < 13; ++k){
    const int r = rs + 16*k;
    if (r < 196){
      float s = 0.f;
      #pragma unroll
      for (int c = 0; c < 8; ++c)
        s += STp[((size_t)c<<18) + (size_t)r*1024 + t0 + tl];
      wgt[r][tl] = s;
      m = fminf(m, s);
    }
  }
  red[rs][tl] = m;
  __syncthreads();
  if (tid < 16){
    float mm = red[0][tid];
    #pragma unroll
    for (int i = 1; i < 16; ++i) mm = fminf(mm, red[i][tid]);
    red[0][tid] = mm;
  }
  __syncthreads();
  const float mt = red[0][tl];
  float sum = 0.f;
  for (int k = 0; k < 13; ++k){
    const int r = rs + 16*k;
    if (r < 196){
      float p = EXP2(PRESCALE*(mt - wgt[r][tl]));
      wgt[r][tl] = p;
      sum += p;
    }
  }
  __syncthreads();
  red[rs][tl] = sum;
  __syncthreads();
  if (tid < 16){
    float ss = 0.f;
    #pragma unroll
    for (int i = 0; i < 16; ++i) ss += red[i][tid];
    red[0][tid] = 1.f / (ss * 196.f);
  }
  __syncthreads();
  const float inv = red[0][tl];
  for (int k = 0; k < 13; ++k){
    const int r = rs + 16*k;
    if (r < 196) wgt[r][tl] *= inv;
  }
  __syncthreads();

  const int e = e0 + (tid & 63), tq = tid >> 6;
  float acc[4] = {0.f, 0.f, 0.f, 0.f};
  const float* ip = img + e;
  #pragma unroll 4
  for (int r = 0; r < 196; ++r){
    const float f = ip[(size_t)r*512];
    float4 w4 = *reinterpret_cast<const float4*>(&wgt[r][tq*4]);
    acc[0] += w4.x*f; acc[1] += w4.y*f; acc[2] += w4.z*f; acc[3] += w4.w*f;
  }
  #pragma unroll
  for (int j = 0; j < 4; ++j)
    out[(size_t)(t0 + tq*4 + j)*1024 + e] = acc[j];
}

extern "C" void kernel_launch(void* const* d_in, const int* in_sizes, int n_in,
                              void* d_out, int out_size, void* d_ws, size_t ws_size,
                              hipStream_t stream) {
  const int*   question = (const int*)d_in[0];
  const float* img_feat = (const float*)d_in[1];
  const float* emb      = (const float*)d_in[2];
  const float* W_img    = (const float*)d_in[3];
  const float* b_img    = (const float*)d_in[4];
  const float* W_ai     = (const float*)d_in[5];
  const float* W_aw     = (const float*)d_in[6];
  const float* b_aw     = (const float*)d_in[7];
  const float* w_att    = (const float*)d_in[8];
  // d_in[9] = b_att: constant pre-softmax shift -> cancels in softmax.
  float* out = (float*)d_out;

  char* ws = (char*)d_ws;
  s16*   Wb    = (s16*)(ws);                  // 3x512x512 bf16 = 1572864 B
  s16*   Xb    = (s16*)(ws + 1572864);        // 256x512 bf16   = 262144 B
  s16*   Eb    = (s16*)(ws + 1835008);        // 1024x512 bf16  = 1048576 B
  float* img   = (float*)(ws + 2883584);      // 256x512 f32    = 524288 B
  s16*   img_b = (s16*)(ws + 3407872);        // 256x512 bf16   = 262144 B
  // (ws + 3670016 .. 4194304: unused, was AI)
  float* AWT4  = (float*)(ws + 4194304);      // 128x1024x4 f32 = 2097152 B
  float* STp   = (float*)(ws + 6291456);      // 8x256x1024 f32 = 8388608 B

  hipLaunchKernelGGL(k_prep,  dim3(512),    dim3(256), 0, stream,
                     W_img, W_ai, W_aw, img_feat, question, emb, Wb, Xb, Eb, out);
  hipLaunchKernelGGL(k_gemms, dim3(160),    dim3(256), 0, stream,
                     Xb, Wb, Wb + 2*262144, Eb, b_img, b_aw, img, img_b, AWT4);
  hipLaunchKernelGGL(k_score, dim3(26,8,2), dim3(512), 0, stream,
                     img_b, Wb + 262144, AWT4, w_att, STp);
  hipLaunchKernelGGL(k_ctx,   dim3(64,8),   dim3(256), 0, stream, STp, img, out);
}